// Round 3
// baseline (10025.820 us; speedup 1.0000x reference)
//
#include <hip/hip_runtime.h>
#include <cstdint>
#include <cstddef>

// Problem constants
#define N_NEU   4096
#define N_IN    1024
#define B_SZ    8
#define T_STEPS 500
#define NBLK    512

// ws layout:
//   [0)      int counters[64*16]          4 KB   (grid barrier, 64B-padded)
//   [4096)   u64 recmask[2][2][8][64]    16 KB   (dbuf exc/inh spike masks)
//   [20480)  float ffdrive[T][B][N]      65.5 MB (optional precomputed FF drive)
#define WS_CNT_OFF   0
#define WS_MASK_OFF  4096
#define WS_FF_OFF    20480
#define WS_NEED_FF   (20480 + (size_t)T_STEPS * B_SZ * N_NEU * 4)

__global__ __launch_bounds__(256) void snn_init(int* __restrict__ counters,
                                                unsigned long long* __restrict__ recmask) {
    int tid = threadIdx.x;
    for (int k = tid; k < 64 * 16; k += 256) counters[k] = 0;
    for (int k = tid; k < 2048; k += 256) recmask[k] = 0ULL;
}

// extract set-bit indices (bit b of lane l's word -> index l*64+b) into lds,
// globally ascending. Returns total count. One wave (64 threads).
__device__ __forceinline__ int extract_bits(unsigned long long m, int* lds) {
    const int lane = threadIdx.x;
    int pc  = __popcll(m);
    int sum = pc;
#pragma unroll
    for (int d = 1; d < 64; d <<= 1) {
        int o = __shfl_up(sum, d, 64);
        if (lane >= d) sum += o;
    }
    int off   = sum - pc;           // exclusive prefix
    int total = __shfl(sum, 63, 64);
    int base  = lane << 6;
    while (m) {
        int b = __builtin_ctzll(m);
        lds[off++] = base + b;
        m &= m - 1ULL;
    }
    return total;
}

// sum of round(w*s) over listed rows, ascending order (bit-exact vs reference)
__device__ __forceinline__ float gather_rows(const int* __restrict__ lst, int n,
                                             const float* __restrict__ base, float s) {
#pragma clang fp contract(off)
    float acc = 0.0f;
    int k = 0;
    for (; k + 4 <= n; k += 4) {
        int j0 = lst[k], j1 = lst[k+1], j2 = lst[k+2], j3 = lst[k+3];
        float w0 = base[(size_t)j0 << 12];
        float w1 = base[(size_t)j1 << 12];
        float w2 = base[(size_t)j2 << 12];
        float w3 = base[(size_t)j3 << 12];
        acc += w0 * s; acc += w1 * s; acc += w2 * s; acc += w3 * s;
    }
    for (; k < n; ++k) {
        float w = base[(size_t)lst[k] << 12];
        acc += w * s;
    }
    return acc;
}

// build 16 ff mask words for (b,t) via ballots; lane k (<16) keeps word k
__device__ __forceinline__ unsigned long long ff_word(const float* __restrict__ isp) {
    const int lane = threadIdx.x;
    unsigned long long myw = 0ULL;
#pragma unroll
    for (int k = 0; k < 16; ++k) {
        unsigned long long m = __ballot(isp[(k << 6) + lane] > 0.5f);
        if (lane == k) myw = m;
    }
    return (lane < 16) ? myw : 0ULL;
}

// Precompute FF drive for all (t,b): ffdrive[(t*B+b)*N + i], bit-exact order.
// bid = tile*64 + chunk -> bid%8 == chunk%8: Wff slice L2-resident per XCD.
__global__ __launch_bounds__(64) void snn_ffpre(const float* __restrict__ inspk,
                                                const float* __restrict__ Wff,
                                                const float* __restrict__ sfff,
                                                const int*   __restrict__ ci,
                                                float*       __restrict__ ffdrive) {
#pragma clang fp contract(off)
    const int lane  = threadIdx.x;
    const int chunk = blockIdx.x & 63;
    const int tile  = blockIdx.x >> 6;     // 80 tiles of 50 (t,b) pairs
    const int i     = (chunk << 6) + lane;
    const float s_ff = sfff[ci[i]];
    __shared__ int lds_ff[N_IN];
    for (int p = tile * 50; p < tile * 50 + 50; ++p) {
        const int t = p >> 3, b = p & 7;
        const float* isp = inspk + ((size_t)b * T_STEPS + t) * N_IN;
        const int n = extract_bits(ff_word(isp), lds_ff);
        __syncthreads();
        float acc = gather_rows(lds_ff, n, Wff + i, s_ff);
        ffdrive[((size_t)t * B_SZ + b) * N_NEU + i] = acc;
        __syncthreads();
    }
}

__global__ __launch_bounds__(64) void snn_run(
    const float* __restrict__ W,       // (N,N) row j = presyn
    const float* __restrict__ Wff,     // (NI,N)
    const float* __restrict__ sf,      // (2,2)
    const float* __restrict__ sfff,    // (1,2)
    const int*   __restrict__ ci,      // (N)
    const float* __restrict__ inspk,   // (B,T,NI) — fallback path only
    float*       __restrict__ out,     // (B,T,N)
    const float* __restrict__ ffdrive,
    int use_ffpre,
    int*         __restrict__ counters,
    unsigned long long* __restrict__ recmask)
{
#pragma clang fp contract(off)
    const int lane  = threadIdx.x;
    const int b     = blockIdx.x >> 6;
    const int chunk = blockIdx.x & 63;   // same chunk all b -> same XCD
    const int i     = (chunk << 6) + lane;
    const int c     = ci[i];

    const float s_exc = sf[c];
    const float s_inh = sf[2 + c];
    const float s_ff  = sfff[c];

    __shared__ int lds_exc[N_NEU];
    __shared__ int lds_inh[N_NEU];
    __shared__ int lds_ff[N_IN];

    // state lives in registers for all 500 steps
    float v = -70.0f, rf = 0.0f;
    float h0 = 0.0f, h1 = 0.0f, h2 = 0.0f, h3 = 0.0f;
    float g0 = 0.0f, g1 = 0.0f, g2 = 0.0f, g3 = 0.0f;

    const float aR0 = expf(-0.1f / 0.5f);
    const float aR1 = expf(-0.1f / 2.0f);
    const float aD0 = expf(-0.1f / 2.0f);
    const float aD1 = expf(-0.1f / 100.0f);
    const float aD2 = expf(-0.1f / 5.0f);
    const float kmem   = c ? (0.1f / 10.0f) : (0.1f / 20.0f);
    const float rsteps = c ? 10.0f : 20.0f;

    const int cslot = chunk << 4;     // my barrier counter (64B padded)
    int target = 0;

    for (int t = 0; t < T_STEPS; ++t) {
        const int buf = t & 1;
        // issue independent ffd load early
        float ffd = 0.0f;
        if (use_ffpre)
            ffd = ffdrive[((size_t)t * B_SZ + b) * N_NEU + i];

        unsigned long long me_w = __hip_atomic_load(
            &recmask[((buf * 2 + 0) * 8 + b) * 64 + lane],
            __ATOMIC_RELAXED, __HIP_MEMORY_SCOPE_AGENT);
        unsigned long long mi_w = __hip_atomic_load(
            &recmask[((buf * 2 + 1) * 8 + b) * 64 + lane],
            __ATOMIC_RELAXED, __HIP_MEMORY_SCOPE_AGENT);
        const int n_exc = extract_bits(me_w, lds_exc);
        const int n_inh = extract_bits(mi_w, lds_inh);
        int n_ff = 0;
        if (!use_ffpre) {
            const float* isp = inspk + ((size_t)b * T_STEPS + t) * N_IN;
            n_ff = extract_bits(ff_word(isp), lds_ff);
        }
        __syncthreads();

        const float exc = gather_rows(lds_exc, n_exc, W + i, s_exc);
        const float inh = gather_rows(lds_inh, n_inh, W + i, s_inh);
        if (!use_ffpre)
            ffd = gather_rows(lds_ff, n_ff, Wff + i, s_ff);

        // ---- neuron update (identical fp op sequence to R1/R2: bit-exact) ----
        const float d0 = exc;
        const float d1 = 0.5f * exc;
        const float d2 = inh;
        const float d3 = ffd;

        h0 = fmaf(h0, aR0, d0);
        h1 = fmaf(h1, aR1, d1);
        h2 = fmaf(h2, aR0, d2);
        h3 = fmaf(h3, aR0, d3);
        g0 = fmaf(g0, aD0, (1.0f - aD0) * h0);
        g1 = fmaf(g1, aD1, (1.0f - aD1) * h1);
        g2 = fmaf(g2, aD2, (1.0f - aD2) * h2);
        g3 = fmaf(g3, aD0, (1.0f - aD0) * h3);

        const float p0 = g0 * (0.0f - v);
        const float p1 = g1 * (0.0f - v);
        const float p2 = g2 * (-80.0f - v);
        const float p3 = g3 * (0.0f - v);
        const float Isyn = ((p0 + p1) + p2) + p3;

        float vn = fmaf(kmem, (-70.0f - v) + Isyn / 10.0f, v);
        const bool refr = rf > 0.0f;
        if (refr) vn = -65.0f;
        const float sn = (!refr && (vn > -50.0f)) ? 1.0f : 0.0f;
        const bool spk = sn > 0.5f;
        v  = spk ? -65.0f : vn;
        rf = spk ? rsteps : fmaxf(rf - 1.0f, 0.0f);

        out[((size_t)b * T_STEPS + t) * N_NEU + i] = sn;

        // next step's spike masks
        const unsigned long long new_e = __ballot(spk && (c == 0));
        const unsigned long long new_i = __ballot(spk && (c == 1));
        if (lane == 0) {
            const int nbuf = (t + 1) & 1;
            __hip_atomic_store(&recmask[((nbuf * 2 + 0) * 8 + b) * 64 + chunk],
                               new_e, __ATOMIC_RELAXED, __HIP_MEMORY_SCOPE_AGENT);
            __hip_atomic_store(&recmask[((nbuf * 2 + 1) * 8 + b) * 64 + chunk],
                               new_i, __ATOMIC_RELAXED, __HIP_MEMORY_SCOPE_AGENT);
        }

        // ---- grid barrier: 64 padded counters, 8 increments each per step ----
        __syncthreads();
        target += NBLK / 64;
        if (lane == 0)
            __hip_atomic_fetch_add(&counters[cslot], 1,
                                   __ATOMIC_RELEASE, __HIP_MEMORY_SCOPE_AGENT);
        for (;;) {
            int cv = __hip_atomic_load(&counters[lane << 4],
                                       __ATOMIC_ACQUIRE, __HIP_MEMORY_SCOPE_AGENT);
            if (__ballot(cv >= target) == ~0ULL) break;
            __builtin_amdgcn_s_sleep(4);
        }
        __syncthreads();
    }
}

extern "C" void kernel_launch(void* const* d_in, const int* in_sizes, int n_in,
                              void* d_out, int out_size, void* d_ws, size_t ws_size,
                              hipStream_t stream) {
    const float* inspk = (const float*)d_in[0];
    const float* W     = (const float*)d_in[1];
    const float* Wff   = (const float*)d_in[2];
    const float* sf    = (const float*)d_in[3];
    const float* sfff  = (const float*)d_in[4];
    const int*   ci    = (const int*)d_in[5];

    float* out = (float*)d_out;
    int*                counters = (int*)((char*)d_ws + WS_CNT_OFF);
    unsigned long long* recmask  = (unsigned long long*)((char*)d_ws + WS_MASK_OFF);
    float*              ffdrive  = (float*)((char*)d_ws + WS_FF_OFF);
    const int use_ffpre = (ws_size >= WS_NEED_FF) ? 1 : 0;

    snn_init<<<1, 256, 0, stream>>>(counters, recmask);
    if (use_ffpre)
        snn_ffpre<<<80 * 64, 64, 0, stream>>>(inspk, Wff, sfff, ci, ffdrive);
    snn_run<<<NBLK, 64, 0, stream>>>(W, Wff, sf, sfff, ci, inspk, out,
                                     ffdrive, use_ffpre, counters, recmask);
}

// Round 4
// 3185.360 us; speedup vs baseline: 3.1475x; 3.1475x over previous
//
#include <hip/hip_runtime.h>
#include <cstdint>
#include <cstddef>

// Problem constants
#define N_NEU   4096
#define N_IN    1024
#define B_SZ    8
#define T_STEPS 500
#define NBLK    512

// ws layout:
//   [0)      int cnt[8*64]               2 KB  (per-batch arrival counters, 256B apart)
//   [2048)   u64 recmask[2][2][8][64]   16 KB  (dbuf exc/inh spike masks)
//   [18432)  float ffdrive[T][B][N]     65.5 MB (optional precomputed FF drive)
#define WS_CNT_OFF   0
#define WS_MASK_OFF  2048
#define WS_FF_OFF    18432
#define WS_NEED_FF   (18432 + (size_t)T_STEPS * B_SZ * N_NEU * 4)

__global__ __launch_bounds__(256) void snn_init(int* __restrict__ cnt,
                                                unsigned long long* __restrict__ recmask) {
    int tid = threadIdx.x;
    for (int k = tid; k < 512; k += 256) cnt[k] = 0;
    for (int k = tid; k < 2048; k += 256) recmask[k] = 0ULL;
}

// extract set-bit indices (bit b of lane l's word -> index l*64+b) into lds,
// globally ascending. Returns total count. Operates within one wave.
__device__ __forceinline__ int extract_bits(unsigned long long m, int* lds, int lane) {
    int pc  = __popcll(m);
    int sum = pc;
#pragma unroll
    for (int d = 1; d < 64; d <<= 1) {
        int o = __shfl_up(sum, d, 64);
        if (lane >= d) sum += o;
    }
    int off   = sum - pc;           // exclusive prefix
    int total = __shfl(sum, 63, 64);
    int base  = lane << 6;
    while (m) {
        int bit = __builtin_ctzll(m);
        lds[off++] = base + bit;
        m &= m - 1ULL;
    }
    return total;
}

// sum of round(w*s) over listed rows, ascending order (bit-exact vs reference),
// 32-wide load pipelining (32 independent global loads in flight).
__device__ __forceinline__ float gather_rows(const int* __restrict__ lst, int n,
                                             const float* __restrict__ base, float s) {
#pragma clang fp contract(off)
    float acc = 0.0f;
    int k = 0;
    for (; k + 32 <= n; k += 32) {
        float w[32];
#pragma unroll
        for (int u = 0; u < 32; ++u) w[u] = base[(size_t)lst[k + u] << 12];
#pragma unroll
        for (int u = 0; u < 32; ++u) acc += w[u] * s;
    }
    for (; k + 8 <= n; k += 8) {
        float w[8];
#pragma unroll
        for (int u = 0; u < 8; ++u) w[u] = base[(size_t)lst[k + u] << 12];
#pragma unroll
        for (int u = 0; u < 8; ++u) acc += w[u] * s;
    }
    for (; k < n; ++k) acc += base[(size_t)lst[k] << 12] * s;
    return acc;
}

// build 16 ff mask words for (b,t) via ballots; lane k (<16) keeps word k
__device__ __forceinline__ unsigned long long ff_word(const float* __restrict__ isp, int lane) {
    unsigned long long myw = 0ULL;
#pragma unroll
    for (int k = 0; k < 16; ++k) {
        unsigned long long m = __ballot(isp[(k << 6) + lane] > 0.5f);
        if (lane == k) myw = m;
    }
    return (lane < 16) ? myw : 0ULL;
}

// Precompute FF drive for all (t,b): ffdrive[(t*B+b)*N + i], bit-exact order.
// bid&7 == chunk&7 -> Wff column slice (2 MB) L2-resident per XCD.
__global__ __launch_bounds__(64) void snn_ffpre(const float* __restrict__ inspk,
                                                const float* __restrict__ Wff,
                                                const float* __restrict__ sfff,
                                                const int*   __restrict__ ci,
                                                float*       __restrict__ ffdrive) {
#pragma clang fp contract(off)
    const int lane  = threadIdx.x;
    const int chunk = blockIdx.x & 63;
    const int tile  = blockIdx.x >> 6;     // 80 tiles of 50 (t,b) pairs
    const int i     = (chunk << 6) + lane;
    const float s_ff = sfff[ci[i]];
    __shared__ int lds_ff[N_IN];
    for (int p = tile * 50; p < tile * 50 + 50; ++p) {
        const int t = p >> 3, b = p & 7;
        const float* isp = inspk + ((size_t)b * T_STEPS + t) * N_IN;
        const int n = extract_bits(ff_word(isp, lane), lds_ff, lane);
        float acc = gather_rows(lds_ff, n, Wff + i, s_ff);
        ffdrive[((size_t)t * B_SZ + b) * N_NEU + i] = acc;
    }
}

__global__ __launch_bounds__(128) void snn_run(
    const float* __restrict__ W,       // (N,N) row j = presyn
    const float* __restrict__ Wff,     // (NI,N)
    const float* __restrict__ sf,      // (2,2)
    const float* __restrict__ sfff,    // (1,2)
    const int*   __restrict__ ci,      // (N)
    const float* __restrict__ inspk,   // (B,T,NI) — fallback path only
    float*       __restrict__ out,     // (B,T,N)
    const float* __restrict__ ffdrive,
    int use_ffpre,
    int*         __restrict__ cnt,
    unsigned long long* __restrict__ recmask)
{
#pragma clang fp contract(off)
    const int tid  = threadIdx.x;
    const int lane = tid & 63;
    const int wv   = tid >> 6;
    // bid -> (b, chunk) with chunk-groups pinned per XCD: xcd = bid&7,
    // chunk = xcd*8 + (bid>>6)&7, b = (bid>>3)&7
    const int bid   = blockIdx.x;
    const int b     = (bid >> 3) & 7;
    const int chunk = ((bid & 7) << 3) | ((bid >> 6) & 7);
    const int i     = (chunk << 6) + lane;
    const int c     = ci[i];

    const float s_exc = sf[c];
    const float s_inh = sf[2 + c];
    const float s_ff  = sfff[c];

    __shared__ int   lds_e[N_NEU];
    __shared__ int   lds_i[N_NEU];
    __shared__ int   lds_f[N_IN];
    __shared__ float smem_inh[64];

    int* cntp = cnt + b * 64;   // 256B-padded per-batch counter

    // state lives in wave1's registers for all 500 steps
    float v = -70.0f, rf = 0.0f;
    float h0 = 0.0f, h1 = 0.0f, h2 = 0.0f, h3 = 0.0f;
    float g0 = 0.0f, g1 = 0.0f, g2 = 0.0f, g3 = 0.0f;

    const float aR0 = expf(-0.1f / 0.5f);
    const float aR1 = expf(-0.1f / 2.0f);
    const float aD0 = expf(-0.1f / 2.0f);
    const float aD1 = expf(-0.1f / 100.0f);
    const float aD2 = expf(-0.1f / 5.0f);
    const float kmem   = c ? (0.1f / 10.0f) : (0.1f / 20.0f);
    const float rsteps = c ? 10.0f : 20.0f;

    for (int t = 0; t < T_STEPS; ++t) {
        // ---- per-batch barrier: single-line relaxed poll, no cache maintenance ----
        if (t > 0) {
            const int tgt = t << 6;
            while (__hip_atomic_load(cntp, __ATOMIC_RELAXED, __HIP_MEMORY_SCOPE_AGENT) < tgt)
                __builtin_amdgcn_s_sleep(1);
            asm volatile("" ::: "memory");   // keep mask loads below the poll
        }
        const int buf = t & 1;

        float exc = 0.0f, ffd = 0.0f;
        if (wv == 0) {
            // inh gather (longer list) on wave0
            unsigned long long mw = __hip_atomic_load(
                &recmask[((buf * 2 + 1) * 8 + b) * 64 + lane],
                __ATOMIC_RELAXED, __HIP_MEMORY_SCOPE_AGENT);
            const int n = extract_bits(mw, lds_i, lane);
            smem_inh[lane] = gather_rows(lds_i, n, W + i, s_inh);
        } else {
            if (use_ffpre)
                ffd = ffdrive[((size_t)t * B_SZ + b) * N_NEU + i];
            unsigned long long mw = __hip_atomic_load(
                &recmask[((buf * 2 + 0) * 8 + b) * 64 + lane],
                __ATOMIC_RELAXED, __HIP_MEMORY_SCOPE_AGENT);
            const int n = extract_bits(mw, lds_e, lane);
            exc = gather_rows(lds_e, n, W + i, s_exc);
            if (!use_ffpre) {
                const float* isp = inspk + ((size_t)b * T_STEPS + t) * N_IN;
                const int nf = extract_bits(ff_word(isp, lane), lds_f, lane);
                ffd = gather_rows(lds_f, nf, Wff + i, s_ff);
            }
        }
        __syncthreads();

        if (wv == 1) {
            const float inh = smem_inh[lane];

            // ---- neuron update (identical fp op sequence to R1–R3: bit-exact) ----
            const float d0 = exc;
            const float d1 = 0.5f * exc;
            const float d2 = inh;
            const float d3 = ffd;

            h0 = fmaf(h0, aR0, d0);
            h1 = fmaf(h1, aR1, d1);
            h2 = fmaf(h2, aR0, d2);
            h3 = fmaf(h3, aR0, d3);
            g0 = fmaf(g0, aD0, (1.0f - aD0) * h0);
            g1 = fmaf(g1, aD1, (1.0f - aD1) * h1);
            g2 = fmaf(g2, aD2, (1.0f - aD2) * h2);
            g3 = fmaf(g3, aD0, (1.0f - aD0) * h3);

            const float p0 = g0 * (0.0f - v);
            const float p1 = g1 * (0.0f - v);
            const float p2 = g2 * (-80.0f - v);
            const float p3 = g3 * (0.0f - v);
            const float Isyn = ((p0 + p1) + p2) + p3;

            float vn = fmaf(kmem, (-70.0f - v) + Isyn / 10.0f, v);
            const bool refr = rf > 0.0f;
            if (refr) vn = -65.0f;
            const float sn = (!refr && (vn > -50.0f)) ? 1.0f : 0.0f;
            const bool spk = sn > 0.5f;
            v  = spk ? -65.0f : vn;
            rf = spk ? rsteps : fmaxf(rf - 1.0f, 0.0f);

            out[((size_t)b * T_STEPS + t) * N_NEU + i] = sn;

            // next step's spike masks (relaxed agent atomics complete at IF — R3-verified)
            const unsigned long long new_e = __ballot(spk && (c == 0));
            const unsigned long long new_i = __ballot(spk && (c == 1));
            if (lane == 0) {
                const int nbuf = (t + 1) & 1;
                __hip_atomic_store(&recmask[((nbuf * 2 + 0) * 8 + b) * 64 + chunk],
                                   new_e, __ATOMIC_RELAXED, __HIP_MEMORY_SCOPE_AGENT);
                __hip_atomic_store(&recmask[((nbuf * 2 + 1) * 8 + b) * 64 + chunk],
                                   new_i, __ATOMIC_RELAXED, __HIP_MEMORY_SCOPE_AGENT);
            }
            __builtin_amdgcn_s_waitcnt(0);   // mask stores complete at IF before arrival
            if (lane == 0)
                __hip_atomic_fetch_add(cntp, 1, __ATOMIC_RELAXED, __HIP_MEMORY_SCOPE_AGENT);
        }
        // wave0 proceeds to the next poll; it cannot pass until this block's
        // wave1 has added (own-block arrival included in the count), so all
        // LDS/smem hazards across steps are covered by the barrier itself.
    }
}

extern "C" void kernel_launch(void* const* d_in, const int* in_sizes, int n_in,
                              void* d_out, int out_size, void* d_ws, size_t ws_size,
                              hipStream_t stream) {
    const float* inspk = (const float*)d_in[0];
    const float* W     = (const float*)d_in[1];
    const float* Wff   = (const float*)d_in[2];
    const float* sf    = (const float*)d_in[3];
    const float* sfff  = (const float*)d_in[4];
    const int*   ci    = (const int*)d_in[5];

    float* out = (float*)d_out;
    int*                cnt     = (int*)((char*)d_ws + WS_CNT_OFF);
    unsigned long long* recmask = (unsigned long long*)((char*)d_ws + WS_MASK_OFF);
    float*              ffdrive = (float*)((char*)d_ws + WS_FF_OFF);
    const int use_ffpre = (ws_size >= WS_NEED_FF) ? 1 : 0;

    snn_init<<<1, 256, 0, stream>>>(cnt, recmask);
    if (use_ffpre)
        snn_ffpre<<<80 * 64, 64, 0, stream>>>(inspk, Wff, sfff, ci, ffdrive);
    snn_run<<<NBLK, 128, 0, stream>>>(W, Wff, sf, sfff, ci, inspk, out,
                                      ffdrive, use_ffpre, cnt, recmask);
}

// Round 5
// 2224.318 us; speedup vs baseline: 4.5074x; 1.4321x over previous
//
#include <hip/hip_runtime.h>
#include <cstdint>
#include <cstddef>

// Problem constants
#define N_NEU   4096
#define N_IN    1024
#define B_SZ    8
#define T_STEPS 500
#define NBLK    512

// ws layout:
//   [0)      int seq[8][64]              2 KB  (per-(batch,chunk) publish flags)
//   [2048)   u64 recmask[2][2][8][64]   16 KB  (dbuf exc/inh spike masks)
//   [18432)  float ffdrive[T][B][N]     65.5 MB (optional precomputed FF drive)
#define WS_SEQ_OFF   0
#define WS_MASK_OFF  2048
#define WS_FF_OFF    18432
#define WS_NEED_FF   (18432 + (size_t)T_STEPS * B_SZ * N_NEU * 4)

__global__ __launch_bounds__(256) void snn_init(int* __restrict__ seq,
                                                unsigned long long* __restrict__ recmask) {
    int tid = threadIdx.x;
    for (int k = tid; k < 512; k += 256) seq[k] = 0;
    for (int k = tid; k < 2048; k += 256) recmask[k] = 0ULL;
}

// extract set-bit indices (bit b of lane l's word -> index l*64+b) into lds,
// globally ascending. Returns total count. Operates within one wave.
__device__ __forceinline__ int extract_bits(unsigned long long m, int* lds, int lane) {
    int pc  = __popcll(m);
    int sum = pc;
#pragma unroll
    for (int d = 1; d < 64; d <<= 1) {
        int o = __shfl_up(sum, d, 64);
        if (lane >= d) sum += o;
    }
    int off   = sum - pc;           // exclusive prefix
    int total = __shfl(sum, 63, 64);
    int base  = lane << 6;
    while (m) {
        int bit = __builtin_ctzll(m);
        lds[off++] = base + bit;
        m &= m - 1ULL;
    }
    return total;
}

// sum of round(w*s) over listed rows, ascending order (bit-exact vs reference),
// 64-wide load pipelining (64 independent global loads in flight).
__device__ __forceinline__ float gather_rows(const int* __restrict__ lst, int n,
                                             const float* __restrict__ base, float s) {
#pragma clang fp contract(off)
    float acc = 0.0f;
    int k = 0;
    for (; k + 64 <= n; k += 64) {
        float w[64];
#pragma unroll
        for (int u = 0; u < 64; ++u) w[u] = base[(size_t)lst[k + u] << 12];
#pragma unroll
        for (int u = 0; u < 64; ++u) acc += w[u] * s;
    }
    for (; k + 16 <= n; k += 16) {
        float w[16];
#pragma unroll
        for (int u = 0; u < 16; ++u) w[u] = base[(size_t)lst[k + u] << 12];
#pragma unroll
        for (int u = 0; u < 16; ++u) acc += w[u] * s;
    }
    for (; k < n; ++k) acc += base[(size_t)lst[k] << 12] * s;
    return acc;
}

// build 16 ff mask words for (b,t) via ballots; lane k (<16) keeps word k
__device__ __forceinline__ unsigned long long ff_word(const float* __restrict__ isp, int lane) {
    unsigned long long myw = 0ULL;
#pragma unroll
    for (int k = 0; k < 16; ++k) {
        unsigned long long m = __ballot(isp[(k << 6) + lane] > 0.5f);
        if (lane == k) myw = m;
    }
    return (lane < 16) ? myw : 0ULL;
}

// Precompute FF drive for all (t,b): ffdrive[(t*B+b)*N + i], bit-exact order.
__global__ __launch_bounds__(64) void snn_ffpre(const float* __restrict__ inspk,
                                                const float* __restrict__ Wff,
                                                const float* __restrict__ sfff,
                                                const int*   __restrict__ ci,
                                                float*       __restrict__ ffdrive) {
#pragma clang fp contract(off)
    const int lane  = threadIdx.x;
    const int chunk = blockIdx.x & 63;
    const int tile  = blockIdx.x >> 6;     // 160 tiles of 25 (t,b) pairs
    const int i     = (chunk << 6) + lane;
    const float s_ff = sfff[ci[i]];
    __shared__ int lds_ff[N_IN];
    for (int p = tile * 25; p < tile * 25 + 25; ++p) {
        const int t = p >> 3, b = p & 7;
        const float* isp = inspk + ((size_t)b * T_STEPS + t) * N_IN;
        const int n = extract_bits(ff_word(isp, lane), lds_ff, lane);
        float acc = gather_rows(lds_ff, n, Wff + i, s_ff);
        ffdrive[((size_t)t * B_SZ + b) * N_NEU + i] = acc;
    }
}

__global__ __launch_bounds__(128) void snn_run(
    const float* __restrict__ W,       // (N,N) row j = presyn
    const float* __restrict__ Wff,     // (NI,N)
    const float* __restrict__ sf,      // (2,2)
    const float* __restrict__ sfff,    // (1,2)
    const int*   __restrict__ ci,      // (N)
    const float* __restrict__ inspk,   // (B,T,NI) — fallback path only
    float*       __restrict__ out,     // (B,T,N)
    const float* __restrict__ ffdrive,
    int use_ffpre,
    int*         __restrict__ seq,
    unsigned long long* __restrict__ recmask)
{
#pragma clang fp contract(off)
    const int tid  = threadIdx.x;
    const int lane = tid & 63;
    const int wv   = tid >> 6;
    // bid -> (b, chunk) with chunk-groups pinned per XCD (bid%8 assumed XCD)
    const int bid   = blockIdx.x;
    const int b     = (bid >> 3) & 7;
    const int chunk = ((bid & 7) << 3) | ((bid >> 6) & 7);
    const int i     = (chunk << 6) + lane;
    const int c     = ci[i];

    const float s_exc = sf[c];
    const float s_inh = sf[2 + c];
    const float s_ff  = sfff[c];

    __shared__ int   lds_e[N_NEU];
    __shared__ int   lds_i[N_NEU];
    __shared__ int   lds_f[N_IN];
    __shared__ float smem_inh[64];

    int* seqb = seq + b * 64;   // my batch's 64 packed publish flags

    // state lives in wave1's registers for all 500 steps
    float v = -70.0f, rf = 0.0f;
    float h0 = 0.0f, h1 = 0.0f, h2 = 0.0f, h3 = 0.0f;
    float g0 = 0.0f, g1 = 0.0f, g2 = 0.0f, g3 = 0.0f;

    const float aR0 = expf(-0.1f / 0.5f);
    const float aR1 = expf(-0.1f / 2.0f);
    const float aD0 = expf(-0.1f / 2.0f);
    const float aD1 = expf(-0.1f / 100.0f);
    const float aD2 = expf(-0.1f / 5.0f);
    const float kmem   = c ? (0.1f / 10.0f) : (0.1f / 20.0f);
    const float rsteps = c ? 10.0f : 20.0f;

    for (int t = 0; t < T_STEPS; ++t) {
        // ---- sync: wait until every chunk of this batch has published step t's
        // masks (seq == t, stored after a waitcnt that drained the mask stores).
        // Lane-parallel poll of 64 packed words; relaxed -> no cache maintenance.
        if (t > 0) {
            for (;;) {
                int sv = __hip_atomic_load(&seqb[lane], __ATOMIC_RELAXED,
                                           __HIP_MEMORY_SCOPE_AGENT);
                if (__ballot(sv >= t) == ~0ULL) break;
                __builtin_amdgcn_s_sleep(1);
            }
            asm volatile("" ::: "memory");   // keep mask loads below the poll
        }
        const int buf = t & 1;

        float exc = 0.0f, ffd = 0.0f;
        if (wv == 0) {
            // inh gather (longer list) on wave0
            unsigned long long mw = __hip_atomic_load(
                &recmask[((buf * 2 + 1) * 8 + b) * 64 + lane],
                __ATOMIC_RELAXED, __HIP_MEMORY_SCOPE_AGENT);
            const int n = extract_bits(mw, lds_i, lane);
            smem_inh[lane] = gather_rows(lds_i, n, W + i, s_inh);
        } else {
            if (use_ffpre)
                ffd = ffdrive[((size_t)t * B_SZ + b) * N_NEU + i];
            unsigned long long mw = __hip_atomic_load(
                &recmask[((buf * 2 + 0) * 8 + b) * 64 + lane],
                __ATOMIC_RELAXED, __HIP_MEMORY_SCOPE_AGENT);
            const int n = extract_bits(mw, lds_e, lane);
            exc = gather_rows(lds_e, n, W + i, s_exc);
            if (!use_ffpre) {
                const float* isp = inspk + ((size_t)b * T_STEPS + t) * N_IN;
                const int nf = extract_bits(ff_word(isp, lane), lds_f, lane);
                ffd = gather_rows(lds_f, nf, Wff + i, s_ff);
            }
        }
        __syncthreads();

        if (wv == 1) {
            const float inh = smem_inh[lane];

            // ---- neuron update (identical fp op sequence to R1–R4: bit-exact) ----
            const float d0 = exc;
            const float d1 = 0.5f * exc;
            const float d2 = inh;
            const float d3 = ffd;

            h0 = fmaf(h0, aR0, d0);
            h1 = fmaf(h1, aR1, d1);
            h2 = fmaf(h2, aR0, d2);
            h3 = fmaf(h3, aR0, d3);
            g0 = fmaf(g0, aD0, (1.0f - aD0) * h0);
            g1 = fmaf(g1, aD1, (1.0f - aD1) * h1);
            g2 = fmaf(g2, aD2, (1.0f - aD2) * h2);
            g3 = fmaf(g3, aD0, (1.0f - aD0) * h3);

            const float p0 = g0 * (0.0f - v);
            const float p1 = g1 * (0.0f - v);
            const float p2 = g2 * (-80.0f - v);
            const float p3 = g3 * (0.0f - v);
            const float Isyn = ((p0 + p1) + p2) + p3;

            float vn = fmaf(kmem, (-70.0f - v) + Isyn / 10.0f, v);
            const bool refr = rf > 0.0f;
            if (refr) vn = -65.0f;
            const float sn = (!refr && (vn > -50.0f)) ? 1.0f : 0.0f;
            const bool spk = sn > 0.5f;
            v  = spk ? -65.0f : vn;
            rf = spk ? rsteps : fmaxf(rf - 1.0f, 0.0f);

            // publish next step's masks, then the seq flag, then the output
            // (out store kept off the critical chain)
            const unsigned long long new_e = __ballot(spk && (c == 0));
            const unsigned long long new_i = __ballot(spk && (c == 1));
            if (lane == 0) {
                const int nbuf = (t + 1) & 1;
                __hip_atomic_store(&recmask[((nbuf * 2 + 0) * 8 + b) * 64 + chunk],
                                   new_e, __ATOMIC_RELAXED, __HIP_MEMORY_SCOPE_AGENT);
                __hip_atomic_store(&recmask[((nbuf * 2 + 1) * 8 + b) * 64 + chunk],
                                   new_i, __ATOMIC_RELAXED, __HIP_MEMORY_SCOPE_AGENT);
            }
            __builtin_amdgcn_s_waitcnt(0);   // mask stores complete at IF first
            if (lane == 0)
                __hip_atomic_store(&seqb[chunk], t + 1,
                                   __ATOMIC_RELAXED, __HIP_MEMORY_SCOPE_AGENT);
            out[((size_t)b * T_STEPS + t) * N_NEU + i] = sn;
        }
        // wave0 proceeds to the next poll; it cannot pass until this block's
        // own wave1 publishes seq=t+1 (after consuming smem_inh), so all
        // LDS/smem cross-step hazards are covered by the poll itself.
    }
}

extern "C" void kernel_launch(void* const* d_in, const int* in_sizes, int n_in,
                              void* d_out, int out_size, void* d_ws, size_t ws_size,
                              hipStream_t stream) {
    const float* inspk = (const float*)d_in[0];
    const float* W     = (const float*)d_in[1];
    const float* Wff   = (const float*)d_in[2];
    const float* sf    = (const float*)d_in[3];
    const float* sfff  = (const float*)d_in[4];
    const int*   ci    = (const int*)d_in[5];

    float* out = (float*)d_out;
    int*                seq     = (int*)((char*)d_ws + WS_SEQ_OFF);
    unsigned long long* recmask = (unsigned long long*)((char*)d_ws + WS_MASK_OFF);
    float*              ffdrive = (float*)((char*)d_ws + WS_FF_OFF);
    const int use_ffpre = (ws_size >= WS_NEED_FF) ? 1 : 0;

    snn_init<<<1, 256, 0, stream>>>(seq, recmask);
    if (use_ffpre)
        snn_ffpre<<<160 * 64, 64, 0, stream>>>(inspk, Wff, sfff, ci, ffdrive);
    snn_run<<<NBLK, 128, 0, stream>>>(W, Wff, sf, sfff, ci, inspk, out,
                                      ffdrive, use_ffpre, seq, recmask);
}